// Round 2
// baseline (16.316 us; speedup 1.0000x reference)
//
#include <hip/hip_runtime.h>

#define BATCH 1024
#define FEAT_DIM 128
#define NUM_CLASSES 100000
#define TAG 0x5A5A5A5Au   // != 0xAAAAAAAA poison

// Fused single-kernel center loss:
//   grid = 256 blocks x 256 threads; each 64-lane wave owns one row:
//   squared distance to its labeled center -> rowsq[row] (+ release tag).
//   Block 0 then acquire-spins on all 1024 tags and does the final
//   fixed-order reduction -> out[0]. No float atomics => deterministic.
__global__ __launch_bounds__(256) void centerloss_fused(
    const float* __restrict__ x,
    const int* __restrict__ labels,
    const float* __restrict__ centers,
    float* rowsq,        // d_ws + 0    : 1024 floats
    unsigned* tags,      // d_ws + 4096 : 1024 u32
    float* out) {

    const int wave = threadIdx.x >> 6;           // 0..3
    const int lane = threadIdx.x & 63;           // 0..63
    const int row  = blockIdx.x * 4 + wave;      // 0..1023

    const long long lbl = (long long)labels[row];

    // 64 lanes x float2 = 128 floats = one full row (coalesced 8B/lane)
    const float2 xa = reinterpret_cast<const float2*>(x + (long long)row * FEAT_DIM)[lane];
    const float2 ca = reinterpret_cast<const float2*>(centers + lbl * FEAT_DIM)[lane];
    const float dx = xa.x - ca.x;
    const float dy = xa.y - ca.y;
    float s = dx * dx + dy * dy;

    // wave64 shuffle reduction (fixed order -> deterministic)
    #pragma unroll
    for (int o = 32; o > 0; o >>= 1)
        s += __shfl_down(s, o, 64);

    if (lane == 0) {
        // value at agent scope (cross-XCD visible), then release-tag
        __hip_atomic_store(&rowsq[row], s, __ATOMIC_RELAXED, __HIP_MEMORY_SCOPE_AGENT);
        __hip_atomic_store(&tags[row], TAG, __ATOMIC_RELEASE, __HIP_MEMORY_SCOPE_AGENT);
    }

    if (blockIdx.x != 0) return;

    // ---- block 0: wait for all rows, then fixed-order reduce ----
    const int t = threadIdx.x;
    #pragma unroll
    for (int k = 0; k < 4; ++k) {
        const int i = t * 4 + k;
        while (__hip_atomic_load(&tags[i], __ATOMIC_ACQUIRE,
                                 __HIP_MEMORY_SCOPE_AGENT) != TAG)
            __builtin_amdgcn_s_sleep(1);
    }

    float part = 0.0f;
    #pragma unroll
    for (int k = 0; k < 4; ++k) {
        const int i = t * 4 + k;
        part += __hip_atomic_load(&rowsq[i], __ATOMIC_RELAXED,
                                  __HIP_MEMORY_SCOPE_AGENT);
    }

    #pragma unroll
    for (int o = 32; o > 0; o >>= 1)
        part += __shfl_down(part, o, 64);

    __shared__ float wsum[4];
    if (lane == 0)
        wsum[wave] = part;
    __syncthreads();

    if (t == 0) {
        const float tot = (wsum[0] + wsum[1]) + (wsum[2] + wsum[3]);
        out[0] = tot * (1.0f / ((float)BATCH * (float)NUM_CLASSES));
    }
}

extern "C" void kernel_launch(void* const* d_in, const int* in_sizes, int n_in,
                              void* d_out, int out_size, void* d_ws, size_t ws_size,
                              hipStream_t stream) {
    const float* x       = (const float*)d_in[0];
    const int*   labels  = (const int*)d_in[1];
    const float* centers = (const float*)d_in[2];
    float*       out     = (float*)d_out;
    float*       rowsq   = (float*)d_ws;                       // 4 KB
    unsigned*    tags    = (unsigned*)((char*)d_ws + 4096);    // 4 KB

    centerloss_fused<<<BATCH / 4, 256, 0, stream>>>(x, labels, centers,
                                                    rowsq, tags, out);
}

// Round 4
// 14.672 us; speedup vs baseline: 1.1120x; 1.1120x over previous
//
#include <hip/hip_runtime.h>

#define BATCH 1024
#define FEAT_DIM 128
#define NUM_CLASSES 100000

// Single fused kernel, "last block finishes" pattern (no spinning):
//   grid = 256 blocks x 256 threads; each 64-lane wave owns one row:
//   ||x_row - centers[label_row]||^2 -> rowsq[row] (agent-scope release).
//   Each block then bumps a counter once; the block seeing old%256==255 is
//   provably the last of THIS call for ANY initial counter value (256
//   consecutive values hit every residue mod 256 exactly once), so it's
//   robust to 0xAA poison and needs no reset. That block acquire-fences and
//   reduces the 1024 partials in a fixed order -> out[0]. Deterministic:
//   reduction order is fixed and values are identical regardless of which
//   block executes it. No float atomics.
__global__ __launch_bounds__(256) void centerloss_fused(
    const float* __restrict__ x,
    const int* __restrict__ labels,
    const float* __restrict__ centers,
    float* rowsq,        // d_ws + 0    : 1024 floats
    unsigned* cnt,       // d_ws + 8192 : 1 u32 (own cache line)
    float* out) {

    const int wave = threadIdx.x >> 6;           // 0..3
    const int lane = threadIdx.x & 63;           // 0..63
    const int row  = blockIdx.x * 4 + wave;      // 0..1023

    const long long lbl = (long long)labels[row];   // wave-uniform -> s_load

    // 64 lanes x float2 = 128 floats = one full row (coalesced 8B/lane)
    const float2 xa = reinterpret_cast<const float2*>(x + (long long)row * FEAT_DIM)[lane];
    const float2 ca = reinterpret_cast<const float2*>(centers + lbl * FEAT_DIM)[lane];
    const float dx = xa.x - ca.x;
    const float dy = xa.y - ca.y;
    float s = dx * dx + dy * dy;

    // wave64 shuffle reduction (fixed order -> deterministic)
    #pragma unroll
    for (int o = 32; o > 0; o >>= 1)
        s += __shfl_down(s, o, 64);

    if (lane == 0)   // agent scope: visible across XCDs once ack'd
        __hip_atomic_store(&rowsq[row], s, __ATOMIC_RELEASE,
                           __HIP_MEMORY_SCOPE_AGENT);

    // __syncthreads emits s_waitcnt vmcnt(0) first -> all 4 waves' release
    // stores have reached the coherence point before the counter bump.
    __syncthreads();

    __shared__ unsigned old_s;
    if (threadIdx.x == 0)
        old_s = __hip_atomic_fetch_add(cnt, 1u, __ATOMIC_RELAXED,
                                       __HIP_MEMORY_SCOPE_AGENT);
    __syncthreads();

    if ((old_s & 255u) != 255u) return;          // not the last block

    // ---- last block: fixed-order final reduction ----
    __builtin_amdgcn_fence(__ATOMIC_ACQUIRE, "agent");

    const int t = threadIdx.x;
    float part = 0.0f;
    #pragma unroll
    for (int k = 0; k < 4; ++k)
        part += __hip_atomic_load(&rowsq[t * 4 + k], __ATOMIC_RELAXED,
                                  __HIP_MEMORY_SCOPE_AGENT);

    #pragma unroll
    for (int o = 32; o > 0; o >>= 1)
        part += __shfl_down(part, o, 64);

    __shared__ float wsum[4];
    if (lane == 0)
        wsum[wave] = part;
    __syncthreads();

    if (t == 0) {
        const float tot = (wsum[0] + wsum[1]) + (wsum[2] + wsum[3]);
        out[0] = tot * (1.0f / ((float)BATCH * (float)NUM_CLASSES));
    }
}

extern "C" void kernel_launch(void* const* d_in, const int* in_sizes, int n_in,
                              void* d_out, int out_size, void* d_ws, size_t ws_size,
                              hipStream_t stream) {
    const float* x       = (const float*)d_in[0];
    const int*   labels  = (const int*)d_in[1];
    const float* centers = (const float*)d_in[2];
    float*       out     = (float*)d_out;
    float*       rowsq   = (float*)d_ws;                       // 4 KB
    unsigned*    cnt     = (unsigned*)((char*)d_ws + 8192);    // own line

    centerloss_fused<<<BATCH / 4, 256, 0, stream>>>(x, labels, centers,
                                                    rowsq, cnt, out);
}

// Round 5
// 10.200 us; speedup vs baseline: 1.5997x; 1.4385x over previous
//
#include <hip/hip_runtime.h>

#define BATCH 1024
#define FEAT_DIM 128
#define NUM_CLASSES 100000
#define NBLK 32          // blocks; 32 rows per block
#define NTHREADS 1024    // 16 waves per block; each wave owns 2 rows

// Single fused kernel, last-block-finishes, LOW coherence traffic:
//   32 blocks x 16 waves; wave w of block b computes rows b*32+w*2 +{0,1}
//   (each row: 64 lanes x float2 = full 128-float row, coalesced).
//   Block reduces its 32 rows to ONE partial (LDS, fixed order), so the
//   cross-XCD traffic is just 32 release stores + 32 same-address RMWs
//   (vs 256+1024 in the previous attempt that cost ~4 us).
//   Counter residue trick: 32 consecutive increments cover every residue
//   mod 32 exactly once -> the block seeing old%32==31 is the last of THIS
//   call for ANY initial counter value (0xAA-poison-proof, no reset).
//   Deterministic: fixed-order reductions, no float atomics; the final
//   result is identical regardless of which block runs the tail.
__global__ __launch_bounds__(NTHREADS) void centerloss_fused(
    const float* __restrict__ x,
    const int* __restrict__ labels,
    const float* __restrict__ centers,
    float* partial,      // d_ws + 0    : 32 floats
    unsigned* cnt,       // d_ws + 4096 : 1 u32 (own cache line)
    float* out) {

    const int wave = threadIdx.x >> 6;                 // 0..15
    const int lane = threadIdx.x & 63;                 // 0..63
    const int row0 = blockIdx.x * 32 + wave * 2;       // first of 2 rows

    // wave-uniform label loads (scalarized by compiler)
    const long long l0 = (long long)labels[row0];
    const long long l1 = (long long)labels[row0 + 1];

    // two independent gather chains per wave (ILP-2 hides HBM latency)
    const float2 xa = reinterpret_cast<const float2*>(x)[(long long)row0 * 64 + lane];
    const float2 xb = reinterpret_cast<const float2*>(x)[(long long)(row0 + 1) * 64 + lane];
    const float2 ca = reinterpret_cast<const float2*>(centers)[l0 * 64 + lane];
    const float2 cb = reinterpret_cast<const float2*>(centers)[l1 * 64 + lane];

    const float d0 = xa.x - ca.x, d1 = xa.y - ca.y;
    const float d2 = xb.x - cb.x, d3 = xb.y - cb.y;
    float s = (d0 * d0 + d1 * d1) + (d2 * d2 + d3 * d3);

    // wave64 shuffle reduction (fixed order -> deterministic)
    #pragma unroll
    for (int o = 32; o > 0; o >>= 1)
        s += __shfl_down(s, o, 64);

    __shared__ float wsum[16];
    __shared__ unsigned old_s;
    if (lane == 0)
        wsum[wave] = s;
    __syncthreads();

    // wave 0 folds the 16 wave-partials and publishes ONE block partial
    if (threadIdx.x < 64) {
        float p = (lane < 16) ? wsum[lane] : 0.0f;
        #pragma unroll
        for (int o = 8; o > 0; o >>= 1)
            p += __shfl_down(p, o, 64);
        if (lane == 0) {
            __hip_atomic_store(&partial[blockIdx.x], p, __ATOMIC_RELAXED,
                               __HIP_MEMORY_SCOPE_AGENT);
            // ACQ_REL: release orders the partial store before the RMW;
            // acquire gives the (potential) last block visibility.
            old_s = __hip_atomic_fetch_add(cnt, 1u, __ATOMIC_ACQ_REL,
                                           __HIP_MEMORY_SCOPE_AGENT);
        }
    }
    __syncthreads();

    if ((old_s & (NBLK - 1)) != (NBLK - 1)) return;    // not last

    // ---- last block: fixed-order reduce of the 32 partials ----
    __builtin_amdgcn_fence(__ATOMIC_ACQUIRE, "agent");
    if (threadIdx.x < 64) {
        float p = (lane < NBLK)
                      ? __hip_atomic_load(&partial[lane], __ATOMIC_RELAXED,
                                          __HIP_MEMORY_SCOPE_AGENT)
                      : 0.0f;
        #pragma unroll
        for (int o = 16; o > 0; o >>= 1)
            p += __shfl_down(p, o, 64);
        if (lane == 0)
            out[0] = p * (1.0f / ((float)BATCH * (float)NUM_CLASSES));
    }
}

extern "C" void kernel_launch(void* const* d_in, const int* in_sizes, int n_in,
                              void* d_out, int out_size, void* d_ws, size_t ws_size,
                              hipStream_t stream) {
    const float* x       = (const float*)d_in[0];
    const int*   labels  = (const int*)d_in[1];
    const float* centers = (const float*)d_in[2];
    float*       out     = (float*)d_out;
    float*       partial = (float*)d_ws;                       // 128 B used
    unsigned*    cnt     = (unsigned*)((char*)d_ws + 4096);    // own line

    centerloss_fused<<<NBLK, NTHREADS, 0, stream>>>(x, labels, centers,
                                                    partial, cnt, out);
}

// Round 6
// 9.398 us; speedup vs baseline: 1.7361x; 1.0853x over previous
//
#include <hip/hip_runtime.h>

#define BATCH 1024
#define FEAT_DIM 128
#define NUM_CLASSES 100000
#define NBLK 16
#define NTHREADS 1024

// Flattened fused center loss. Insight: only the GLOBAL sum is needed, so
// assign work by float4 chunk of the (B,D) domain, not by row:
//   chunk c (16 B) covers x[c>>5][ (c&31)*4 .. +3 ]; 32 consecutive lanes
//   share one row, so the center gather centers[labels[c>>5]] is ALSO
//   coalesced (each 32-lane group reads one contiguous 512 B center row).
// 16 blocks x 1024 threads x 2 chunks = 32768 chunks = full domain.
// Completion: one relaxed RMW per block; 16 consecutive increments cover
// every residue mod 16 exactly once, so old%16==15 identifies the last
// block of THIS call for ANY initial counter value (0xAA-poison-proof,
// no reset, monotone across replays). Last block acquire-fences and does
// a fixed-order 16-element reduce -> out[0]. No float atomics; reduction
// order fixed regardless of which block is last => deterministic.
__global__ __launch_bounds__(NTHREADS) void centerloss_fused(
    const float* __restrict__ x,
    const int* __restrict__ labels,
    const float* __restrict__ centers,
    float* partial,      // d_ws + 0    : 16 floats
    unsigned* cnt,       // d_ws + 4096 : 1 u32 (own cache line)
    float* out) {

    const int wave = threadIdx.x >> 6;                  // 0..15
    const int lane = threadIdx.x & 63;                  // 0..63

    const float4* x4 = reinterpret_cast<const float4*>(x);
    const float4* c4 = reinterpret_cast<const float4*>(centers);

    const int chunk0 = blockIdx.x * 2048 + threadIdx.x; // ILP-2
    const int chunk1 = chunk0 + 1024;

    // row ids and labels (32-lane groups share a row -> L1-hot broadcast)
    const int r0 = chunk0 >> 5, r1 = chunk1 >> 5;
    const long long l0 = (long long)labels[r0];
    const long long l1 = (long long)labels[r1];

    const float4 xa = x4[chunk0];
    const float4 xb = x4[chunk1];
    const float4 ca = c4[l0 * 32 + (chunk0 & 31)];      // coalesced gather
    const float4 cb = c4[l1 * 32 + (chunk1 & 31)];

    const float e0 = xa.x - ca.x, e1 = xa.y - ca.y;
    const float e2 = xa.z - ca.z, e3 = xa.w - ca.w;
    const float f0 = xb.x - cb.x, f1 = xb.y - cb.y;
    const float f2 = xb.z - cb.z, f3 = xb.w - cb.w;
    float s = ((e0 * e0 + e1 * e1) + (e2 * e2 + e3 * e3))
            + ((f0 * f0 + f1 * f1) + (f2 * f2 + f3 * f3));

    // wave64 shuffle reduction (fixed order -> deterministic)
    #pragma unroll
    for (int o = 32; o > 0; o >>= 1)
        s += __shfl_down(s, o, 64);

    __shared__ float wsum[16];
    __shared__ unsigned old_s;
    if (lane == 0)
        wsum[wave] = s;
    __syncthreads();

    // wave 0 folds 16 wave-partials -> ONE block partial + counter bump
    if (threadIdx.x < 64) {
        float p = (lane < 16) ? wsum[lane] : 0.0f;
        #pragma unroll
        for (int o = 8; o > 0; o >>= 1)
            p += __shfl_down(p, o, 64);
        if (lane == 0) {
            __hip_atomic_store(&partial[blockIdx.x], p, __ATOMIC_RELAXED,
                               __HIP_MEMORY_SCOPE_AGENT);
            old_s = __hip_atomic_fetch_add(cnt, 1u, __ATOMIC_ACQ_REL,
                                           __HIP_MEMORY_SCOPE_AGENT);
        }
    }
    __syncthreads();

    if ((old_s & (NBLK - 1)) != (NBLK - 1)) return;     // not last block

    // ---- last block: fixed-order reduce of the 16 partials ----
    __builtin_amdgcn_fence(__ATOMIC_ACQUIRE, "agent");
    if (threadIdx.x < 64) {
        float p = (lane < NBLK)
                      ? __hip_atomic_load(&partial[lane], __ATOMIC_RELAXED,
                                          __HIP_MEMORY_SCOPE_AGENT)
                      : 0.0f;
        #pragma unroll
        for (int o = 8; o > 0; o >>= 1)
            p += __shfl_down(p, o, 64);
        if (lane == 0)
            out[0] = p * (1.0f / ((float)BATCH * (float)NUM_CLASSES));
    }
}

extern "C" void kernel_launch(void* const* d_in, const int* in_sizes, int n_in,
                              void* d_out, int out_size, void* d_ws, size_t ws_size,
                              hipStream_t stream) {
    const float* x       = (const float*)d_in[0];
    const int*   labels  = (const int*)d_in[1];
    const float* centers = (const float*)d_in[2];
    float*       out     = (float*)d_out;
    float*       partial = (float*)d_ws;                       // 64 B used
    unsigned*    cnt     = (unsigned*)((char*)d_ws + 4096);    // own line

    centerloss_fused<<<NBLK, NTHREADS, 0, stream>>>(x, labels, centers,
                                                    partial, cnt, out);
}